// Round 1
// baseline (632.604 us; speedup 1.0000x reference)
//
#include <hip/hip_runtime.h>
#include <hip/hip_bf16.h>
#include <cstdint>
#include <cstddef>

typedef __bf16 bf16;
typedef __bf16 bf16x8 __attribute__((ext_vector_type(8)));
typedef float  f32x4  __attribute__((ext_vector_type(4)));
typedef unsigned short u16x4 __attribute__((ext_vector_type(4)));

static constexpr int D_MODEL = 1024;
static constexpr int HEADS   = 16;
static constexpr int D_KH    = 64;     // per-head dim
static constexpr int D_FF    = 4096;
static constexpr int BATCH   = 4;
static constexpr int SEQ     = 2048;
static constexpr int MROWS   = BATCH * SEQ;  // 8192

__device__ __forceinline__ unsigned short bfbits(float f) {
  return __builtin_bit_cast(unsigned short, (bf16)f);
}

// global -> LDS direct copy, 16B per lane. LDS dest must be linear
// (wave-uniform base + lane*16) -- CK-style addrspace casts via uintptr_t.
__device__ __forceinline__ void gload_lds16(const void* g, void* l) {
  __builtin_amdgcn_global_load_lds(
      (__attribute__((address_space(1))) uint32_t*)(uintptr_t)g,
      (__attribute__((address_space(3))) uint32_t*)(uintptr_t)l, 16, 0, 0);
}

// ---------------- elementwise f32 -> bf16 cast (8/thread) ----------------
__global__ void k_cast_bf16(const float* __restrict__ in, bf16* __restrict__ out) {
  int i = (blockIdx.x * 256 + threadIdx.x) * 8;
  const float4* p = (const float4*)(in + i);
  float4 a = p[0], b = p[1];
  bf16x8 v;
  v[0] = (bf16)a.x; v[1] = (bf16)a.y; v[2] = (bf16)a.z; v[3] = (bf16)a.w;
  v[4] = (bf16)b.x; v[5] = (bf16)b.y; v[6] = (bf16)b.z; v[7] = (bf16)b.w;
  *(bf16x8*)(out + i) = v;
}

// ---------------- W [K,N] f32  ->  Wt [N,K] bf16 (64x64 LDS tiles) -------
__global__ void k_transpose_cast(const float* __restrict__ W, bf16* __restrict__ Wt,
                                 int K, int N) {
  __shared__ float tile[64][65];
  int k0 = blockIdx.x * 64, n0 = blockIdx.y * 64;
  int c = threadIdx.x & 63, r0 = threadIdx.x >> 6;
#pragma unroll
  for (int i = 0; i < 16; ++i) {
    int r = r0 + i * 4;
    tile[r][c] = W[(size_t)(k0 + r) * N + n0 + c];
  }
  __syncthreads();
#pragma unroll
  for (int i = 0; i < 16; ++i) {
    int r = r0 + i * 4;
    Wt[(size_t)(n0 + r) * K + k0 + c] = (bf16)tile[c][r];
  }
}

// ---------------- GEMM: C[M,N] = A[M,K] @ Bt[N,K]^T + bias ---------------
// 128x128 tile, BK=32, 4 waves (each 64x64 = 4x4 16x16 frags), m97 structure.
enum { EP_BF16 = 0, EP_RELU = 1, EP_F32 = 2, EP_VT = 3 };

template <int EPI>
__global__ __launch_bounds__(256, 2) void k_gemm_bt(
    const bf16* __restrict__ A, const bf16* __restrict__ Bt,
    const float* __restrict__ bias, void* __restrict__ Cout,
    int N, int K) {
  __shared__ bf16 As[128 * 32];
  __shared__ bf16 Bs[128 * 32];
  const int tid  = threadIdx.x;
  const int lane = tid & 63;
  const int w = tid >> 6, wr = w >> 1, wc = w & 1;
  const int l15 = lane & 15, l4 = lane >> 4;
  const int srow = tid >> 2, scol = (tid & 3) * 8;
  const bf16* Ag = A + (size_t)(blockIdx.x * 128 + srow) * K + scol;
  const bf16* Bg = Bt + (size_t)(blockIdx.y * 128 + srow) * K + scol;
  char* AsB = (char*)As + tid * 16;
  char* BsB = (char*)Bs + tid * 16;
  f32x4 acc[4][4] = {};
  for (int k0 = 0; k0 < K; k0 += 32) {
    gload_lds16(Ag + k0, AsB);
    gload_lds16(Ag + (size_t)64 * K + k0, AsB + 4096);
    gload_lds16(Bg + k0, BsB);
    gload_lds16(Bg + (size_t)64 * K + k0, BsB + 4096);
    __syncthreads();
    bf16x8 a[4], b[4];
#pragma unroll
    for (int m = 0; m < 4; ++m)
      a[m] = *(const bf16x8*)&As[(wr * 64 + m * 16 + l15) * 32 + l4 * 8];
#pragma unroll
    for (int n = 0; n < 4; ++n)
      b[n] = *(const bf16x8*)&Bs[(wc * 64 + n * 16 + l15) * 32 + l4 * 8];
#pragma unroll
    for (int m = 0; m < 4; ++m)
#pragma unroll
      for (int n = 0; n < 4; ++n)
        acc[m][n] = __builtin_amdgcn_mfma_f32_16x16x32_bf16(a[m], b[n], acc[m][n], 0, 0, 0);
    __syncthreads();
  }
  float bia[4];
#pragma unroll
  for (int n = 0; n < 4; ++n)
    bia[n] = bias[blockIdx.y * 128 + wc * 64 + n * 16 + l15];
#pragma unroll
  for (int m = 0; m < 4; ++m) {
    int row0 = blockIdx.x * 128 + wr * 64 + m * 16 + l4 * 4;
#pragma unroll
    for (int n = 0; n < 4; ++n) {
      int col = blockIdx.y * 128 + wc * 64 + n * 16 + l15;
      if constexpr (EPI == EP_VT) {
        // write V transposed: Vt[b][h][d][s], pack 4 consecutive s
        int bidx = row0 >> 11, s0 = row0 & 2047;
        int hh = col >> 6, dd = col & 63;
        u16x4 pk;
#pragma unroll
        for (int r = 0; r < 4; ++r) pk[r] = bfbits(acc[m][n][r] + bia[n]);
        *(u16x4*)((bf16*)Cout + (((size_t)bidx * HEADS + hh) * D_KH + dd) * SEQ + s0) = pk;
      } else {
#pragma unroll
        for (int r = 0; r < 4; ++r) {
          float v = acc[m][n][r] + bia[n];
          if constexpr (EPI == EP_RELU) v = fmaxf(v, 0.f);
          if constexpr (EPI == EP_F32)
            ((float*)Cout)[(size_t)(row0 + r) * N + col] = v;
          else
            ((bf16*)Cout)[(size_t)(row0 + r) * N + col] = (bf16)v;
        }
      }
    }
  }
}

// ---------------- flash attention -----------------
// grid (SEQ/128, BATCH*HEADS); 4 waves x 32 q-rows. Q in regs; K,V from L2.
__global__ __launch_bounds__(256, 2) void k_attn(
    const bf16* __restrict__ Q, const bf16* __restrict__ Kb,
    const bf16* __restrict__ Vt, const int* __restrict__ mask,
    bf16* __restrict__ O) {
  __shared__ bf16 Pl[4][32][72];  // per-wave P scratch, +8 pad (2-way = free)
  const int lane = threadIdx.x & 63, w = threadIdx.x >> 6;
  const int l15 = lane & 15, l4 = lane >> 4;
  const int bh = blockIdx.y, b = bh >> 4, h = bh & 15;
  const size_t qrow0 = (size_t)b * SEQ + blockIdx.x * 128 + w * 32;
  bf16x8 qf[2][2];
#pragma unroll
  for (int m = 0; m < 2; ++m)
#pragma unroll
    for (int ks = 0; ks < 2; ++ks)
      qf[m][ks] = *(const bf16x8*)&Q[(qrow0 + m * 16 + l15) * D_MODEL + h * 64 + ks * 32 + l4 * 8];
  f32x4 o[2][4] = {};
  float mrun[2][4], lrun[2][4];
#pragma unroll
  for (int m = 0; m < 2; ++m)
#pragma unroll
    for (int r = 0; r < 4; ++r) { mrun[m][r] = -1e30f; lrun[m][r] = 0.f; }
  const bf16* Kbase = Kb + ((size_t)b * SEQ) * D_MODEL + h * 64;
  const bf16* Vbase = Vt + (size_t)bh * D_KH * SEQ;

  for (int kv0 = 0; kv0 < SEQ; kv0 += 64) {
    f32x4 sf[2][4] = {};
    bf16x8 kf[4][2];
#pragma unroll
    for (int n = 0; n < 4; ++n)
#pragma unroll
      for (int ks = 0; ks < 2; ++ks)
        kf[n][ks] = *(const bf16x8*)&Kbase[(size_t)(kv0 + n * 16 + l15) * D_MODEL + ks * 32 + l4 * 8];
#pragma unroll
    for (int m = 0; m < 2; ++m)
#pragma unroll
      for (int n = 0; n < 4; ++n)
#pragma unroll
        for (int ks = 0; ks < 2; ++ks)
          sf[m][n] = __builtin_amdgcn_mfma_f32_16x16x32_bf16(qf[m][ks], kf[n][ks], sf[m][n], 0, 0, 0);
    int mk[4];
#pragma unroll
    for (int n = 0; n < 4; ++n) mk[n] = mask[b * SEQ + kv0 + n * 16 + l15];
#pragma unroll
    for (int m = 0; m < 2; ++m)
#pragma unroll
      for (int n = 0; n < 4; ++n)
#pragma unroll
        for (int r = 0; r < 4; ++r) {
          float v = sf[m][n][r] * 0.125f;  // 1/sqrt(64)
          sf[m][n][r] = (mk[n] == 0) ? -1e30f : v;
        }
    // online softmax: row r of frag m lives in lanes sharing l4, spread over l15
#pragma unroll
    for (int m = 0; m < 2; ++m)
#pragma unroll
      for (int r = 0; r < 4; ++r) {
        float pm = fmaxf(fmaxf(sf[m][0][r], sf[m][1][r]), fmaxf(sf[m][2][r], sf[m][3][r]));
        pm = fmaxf(pm, __shfl_xor(pm, 1));
        pm = fmaxf(pm, __shfl_xor(pm, 2));
        pm = fmaxf(pm, __shfl_xor(pm, 4));
        pm = fmaxf(pm, __shfl_xor(pm, 8));
        float mnew = fmaxf(mrun[m][r], pm);
        float alpha = __expf(mrun[m][r] - mnew);
        mrun[m][r] = mnew;
        float ps = 0.f;
#pragma unroll
        for (int n = 0; n < 4; ++n) {
          float p = __expf(sf[m][n][r] - mnew);
          sf[m][n][r] = p;
          ps += p;
        }
        ps += __shfl_xor(ps, 1);
        ps += __shfl_xor(ps, 2);
        ps += __shfl_xor(ps, 4);
        ps += __shfl_xor(ps, 8);
        lrun[m][r] = lrun[m][r] * alpha + ps;
#pragma unroll
        for (int n = 0; n < 4; ++n) o[m][n][r] *= alpha;
      }
    // P (C-layout) -> LDS -> A-layout frags (wave-private, no barrier needed)
#pragma unroll
    for (int m = 0; m < 2; ++m)
#pragma unroll
      for (int n = 0; n < 4; ++n)
#pragma unroll
        for (int r = 0; r < 4; ++r)
          Pl[w][m * 16 + l4 * 4 + r][n * 16 + l15] = (bf16)sf[m][n][r];
    bf16x8 pa[2][2];
#pragma unroll
    for (int m = 0; m < 2; ++m)
#pragma unroll
      for (int ks = 0; ks < 2; ++ks)
        pa[m][ks] = *(const bf16x8*)&Pl[w][m * 16 + l15][ks * 32 + l4 * 8];
    bf16x8 vf[4][2];
#pragma unroll
    for (int n = 0; n < 4; ++n)
#pragma unroll
      for (int ks = 0; ks < 2; ++ks)
        vf[n][ks] = *(const bf16x8*)&Vbase[(size_t)(n * 16 + l15) * SEQ + kv0 + ks * 32 + l4 * 8];
#pragma unroll
    for (int m = 0; m < 2; ++m)
#pragma unroll
      for (int n = 0; n < 4; ++n)
#pragma unroll
        for (int ks = 0; ks < 2; ++ks)
          o[m][n] = __builtin_amdgcn_mfma_f32_16x16x32_bf16(pa[m][ks], vf[n][ks], o[m][n], 0, 0, 0);
  }
#pragma unroll
  for (int m = 0; m < 2; ++m) {
    float inv[4];
#pragma unroll
    for (int r = 0; r < 4; ++r) inv[r] = 1.0f / lrun[m][r];
#pragma unroll
    for (int n = 0; n < 4; ++n)
#pragma unroll
      for (int r = 0; r < 4; ++r)
        O[(qrow0 + m * 16 + l4 * 4 + r) * D_MODEL + h * 64 + n * 16 + l15] =
            (bf16)(o[m][n][r] * inv[r]);
  }
}

// ---------------- fused residual add + LayerNorm (1 block / row) ---------
__global__ __launch_bounds__(256) void k_add_ln(
    const float* __restrict__ a, const float* __restrict__ b,
    const float* __restrict__ g, const float* __restrict__ be,
    float* __restrict__ yf, bf16* __restrict__ yb) {
  const int t = threadIdx.x;
  const size_t base = (size_t)blockIdx.x * D_MODEL + t * 4;
  float4 va = *(const float4*)(a + base);
  float4 vb = *(const float4*)(b + base);
  float v0 = va.x + vb.x, v1 = va.y + vb.y, v2 = va.z + vb.z, v3 = va.w + vb.w;
  float s  = v0 + v1 + v2 + v3;
  float s2 = v0 * v0 + v1 * v1 + v2 * v2 + v3 * v3;
#pragma unroll
  for (int off = 1; off < 64; off <<= 1) {
    s  += __shfl_xor(s, off);
    s2 += __shfl_xor(s2, off);
  }
  __shared__ float red1[4], red2[4];
  int w = t >> 6;
  if ((t & 63) == 0) { red1[w] = s; red2[w] = s2; }
  __syncthreads();
  s  = red1[0] + red1[1] + red1[2] + red1[3];
  s2 = red2[0] + red2[1] + red2[2] + red2[3];
  float mu  = s * (1.f / D_MODEL);
  float var = s2 * (1.f / D_MODEL) - mu * mu;
  float rstd = rsqrtf(var + 1e-5f);
  float4 vg  = *(const float4*)(g + t * 4);
  float4 vbe = *(const float4*)(be + t * 4);
  float y0 = (v0 - mu) * rstd * vg.x + vbe.x;
  float y1 = (v1 - mu) * rstd * vg.y + vbe.y;
  float y2 = (v2 - mu) * rstd * vg.z + vbe.z;
  float y3 = (v3 - mu) * rstd * vg.w + vbe.w;
  *(float4*)(yf + base) = make_float4(y0, y1, y2, y3);
  if (yb) {
    u16x4 pk = {bfbits(y0), bfbits(y1), bfbits(y2), bfbits(y3)};
    *(u16x4*)(yb + base) = pk;
  }
}

// ---------------- orchestration ----------------
extern "C" void kernel_launch(void* const* d_in, const int* in_sizes, int n_in,
                              void* d_out, int out_size, void* d_ws, size_t ws_size,
                              hipStream_t stream) {
  const float* x   = (const float*)d_in[0];
  const int*  mask = (const int*)d_in[1];
  const float* Wq  = (const float*)d_in[2];
  const float* bq  = (const float*)d_in[3];
  const float* Wk  = (const float*)d_in[4];
  const float* bk_ = (const float*)d_in[5];
  const float* Wv  = (const float*)d_in[6];
  const float* bv  = (const float*)d_in[7];
  const float* Wo  = (const float*)d_in[8];
  const float* bo  = (const float*)d_in[9];
  const float* W1  = (const float*)d_in[10];
  const float* b1  = (const float*)d_in[11];
  const float* W2  = (const float*)d_in[12];
  const float* b2  = (const float*)d_in[13];
  const float* g1  = (const float*)d_in[14];
  const float* be1 = (const float*)d_in[15];
  const float* g2  = (const float*)d_in[16];
  const float* be2 = (const float*)d_in[17];

  char* ws = (char*)d_ws;
  const size_t MB = 1ull << 20;
  // arena (168MB): [0,64) xb/Q/K/Vt phase 1-3, reused as FFN hidden in phase 5
  bf16*  xb   = (bf16*)(ws + 0);         // 16MB, later attention output O
  bf16*  Qb   = (bf16*)(ws + 16 * MB);   // 16MB
  bf16*  Kbuf = (bf16*)(ws + 32 * MB);   // 16MB
  bf16*  Vt   = (bf16*)(ws + 48 * MB);   // 16MB [B,H,64,S]
  bf16*  Hb   = (bf16*)(ws + 0);         // 64MB FFN hidden (reuse)
  float* f32a = (float*)(ws + 64 * MB);  // 32MB attn-proj f32 / ffn f32
  float* x1f  = (float*)(ws + 96 * MB);  // 32MB
  bf16*  x1b  = (bf16*)(ws + 128 * MB);  // 16MB
  bf16*  Wqt  = (bf16*)(ws + 144 * MB);
  bf16*  Wkt  = (bf16*)(ws + 146 * MB);
  bf16*  Wvt  = (bf16*)(ws + 148 * MB);
  bf16*  Wot  = (bf16*)(ws + 150 * MB);
  bf16*  W1t  = (bf16*)(ws + 152 * MB);  // 8MB [4096,1024]
  bf16*  W2t  = (bf16*)(ws + 160 * MB);  // 8MB [1024,4096]
  bf16*  Ob   = xb;

  k_cast_bf16<<<MROWS * D_MODEL / (256 * 8), 256, 0, stream>>>(x, xb);
  k_transpose_cast<<<dim3(16, 16), 256, 0, stream>>>(Wq, Wqt, 1024, 1024);
  k_transpose_cast<<<dim3(16, 16), 256, 0, stream>>>(Wk, Wkt, 1024, 1024);
  k_transpose_cast<<<dim3(16, 16), 256, 0, stream>>>(Wv, Wvt, 1024, 1024);
  k_transpose_cast<<<dim3(16, 16), 256, 0, stream>>>(Wo, Wot, 1024, 1024);
  k_transpose_cast<<<dim3(16, 64), 256, 0, stream>>>(W1, W1t, 1024, 4096);
  k_transpose_cast<<<dim3(64, 16), 256, 0, stream>>>(W2, W2t, 4096, 1024);

  k_gemm_bt<EP_BF16><<<dim3(64, 8), 256, 0, stream>>>(xb, Wqt, bq, Qb, 1024, 1024);
  k_gemm_bt<EP_BF16><<<dim3(64, 8), 256, 0, stream>>>(xb, Wkt, bk_, Kbuf, 1024, 1024);
  k_gemm_bt<EP_VT  ><<<dim3(64, 8), 256, 0, stream>>>(xb, Wvt, bv, Vt, 1024, 1024);

  k_attn<<<dim3(16, 64), 256, 0, stream>>>(Qb, Kbuf, Vt, mask, Ob);

  k_gemm_bt<EP_F32><<<dim3(64, 8), 256, 0, stream>>>(Ob, Wot, bo, f32a, 1024, 1024);
  k_add_ln<<<MROWS, 256, 0, stream>>>(x, f32a, g1, be1, x1f, x1b);

  k_gemm_bt<EP_RELU><<<dim3(64, 32), 256, 0, stream>>>(x1b, W1t, b1, Hb, 4096, 1024);
  k_gemm_bt<EP_F32><<<dim3(64, 8), 256, 0, stream>>>(Hb, W2t, b2, f32a, 1024, 4096);
  k_add_ln<<<MROWS, 256, 0, stream>>>(x1f, f32a, g2, be2, (float*)d_out, nullptr);
}

// Round 2
// 485.099 us; speedup vs baseline: 1.3041x; 1.3041x over previous
//
#include <hip/hip_runtime.h>
#include <hip/hip_bf16.h>
#include <cstdint>
#include <cstddef>

typedef __bf16 bf16;
typedef __bf16 bf16x8 __attribute__((ext_vector_type(8)));
typedef float  f32x4  __attribute__((ext_vector_type(4)));
typedef unsigned short u16x4 __attribute__((ext_vector_type(4)));

static constexpr int D_MODEL = 1024;
static constexpr int HEADS   = 16;
static constexpr int D_KH    = 64;     // per-head dim
static constexpr int D_FF    = 4096;
static constexpr int BATCH   = 4;
static constexpr int SEQ     = 2048;
static constexpr int MROWS   = BATCH * SEQ;  // 8192

__device__ __forceinline__ unsigned short bfbits(float f) {
  return __builtin_bit_cast(unsigned short, (bf16)f);
}

// global -> LDS direct copy, 16B per lane. LDS dest must be linear
// (wave-uniform base + lane*16).
__device__ __forceinline__ void gload_lds16(const void* g, void* l) {
  __builtin_amdgcn_global_load_lds(
      (__attribute__((address_space(1))) uint32_t*)(uintptr_t)g,
      (__attribute__((address_space(3))) uint32_t*)(uintptr_t)l, 16, 0, 0);
}

// ---------------- elementwise f32 -> bf16 cast (8/thread) ----------------
__global__ void k_cast_bf16(const float* __restrict__ in, bf16* __restrict__ out) {
  int i = (blockIdx.x * 256 + threadIdx.x) * 8;
  const float4* p = (const float4*)(in + i);
  float4 a = p[0], b = p[1];
  bf16x8 v;
  v[0] = (bf16)a.x; v[1] = (bf16)a.y; v[2] = (bf16)a.z; v[3] = (bf16)a.w;
  v[4] = (bf16)b.x; v[5] = (bf16)b.y; v[6] = (bf16)b.z; v[7] = (bf16)b.w;
  *(bf16x8*)(out + i) = v;
}

// ---------------- W [K,N] f32  ->  Wt [N,K] bf16 (64x64 LDS tiles) -------
__global__ void k_transpose_cast(const float* __restrict__ W, bf16* __restrict__ Wt,
                                 int K, int N) {
  __shared__ float tile[64][65];
  int k0 = blockIdx.x * 64, n0 = blockIdx.y * 64;
  int c = threadIdx.x & 63, r0 = threadIdx.x >> 6;
#pragma unroll
  for (int i = 0; i < 16; ++i) {
    int r = r0 + i * 4;
    tile[r][c] = W[(size_t)(k0 + r) * N + n0 + c];
  }
  __syncthreads();
#pragma unroll
  for (int i = 0; i < 16; ++i) {
    int r = r0 + i * 4;
    Wt[(size_t)(n0 + r) * K + k0 + c] = (bf16)tile[c][r];
  }
}

// ---------------- GEMM: C[M,N] = A[M,K] @ Bt[N,K]^T + bias ---------------
// 128x128 tile, BK=32, 4 waves (each 64x64 = 4x4 16x16 frags), m97 structure.
enum { EP_BF16 = 0, EP_RELU = 1, EP_F32 = 2, EP_VT = 3 };

template <int EPI>
__global__ __launch_bounds__(256, 2) void k_gemm_bt(
    const bf16* __restrict__ A, const bf16* __restrict__ Bt,
    const float* __restrict__ bias, void* __restrict__ Cout,
    int N, int K) {
  __shared__ bf16 As[128 * 32];
  __shared__ bf16 Bs[128 * 32];
  const int tid  = threadIdx.x;
  const int lane = tid & 63;
  const int w = tid >> 6, wr = w >> 1, wc = w & 1;
  const int l15 = lane & 15, l4 = lane >> 4;
  const int srow = tid >> 2, scol = (tid & 3) * 8;
  const bf16* Ag = A + (size_t)(blockIdx.x * 128 + srow) * K + scol;
  const bf16* Bg = Bt + (size_t)(blockIdx.y * 128 + srow) * K + scol;
  char* AsB = (char*)As + tid * 16;
  char* BsB = (char*)Bs + tid * 16;
  f32x4 acc[4][4] = {};
  for (int k0 = 0; k0 < K; k0 += 32) {
    gload_lds16(Ag + k0, AsB);
    gload_lds16(Ag + (size_t)64 * K + k0, AsB + 4096);
    gload_lds16(Bg + k0, BsB);
    gload_lds16(Bg + (size_t)64 * K + k0, BsB + 4096);
    __syncthreads();
    bf16x8 a[4], b[4];
#pragma unroll
    for (int m = 0; m < 4; ++m)
      a[m] = *(const bf16x8*)&As[(wr * 64 + m * 16 + l15) * 32 + l4 * 8];
#pragma unroll
    for (int n = 0; n < 4; ++n)
      b[n] = *(const bf16x8*)&Bs[(wc * 64 + n * 16 + l15) * 32 + l4 * 8];
#pragma unroll
    for (int m = 0; m < 4; ++m)
#pragma unroll
      for (int n = 0; n < 4; ++n)
        acc[m][n] = __builtin_amdgcn_mfma_f32_16x16x32_bf16(a[m], b[n], acc[m][n], 0, 0, 0);
    __syncthreads();
  }
  float bia[4];
#pragma unroll
  for (int n = 0; n < 4; ++n)
    bia[n] = bias[blockIdx.y * 128 + wc * 64 + n * 16 + l15];
#pragma unroll
  for (int m = 0; m < 4; ++m) {
    int row0 = blockIdx.x * 128 + wr * 64 + m * 16 + l4 * 4;
#pragma unroll
    for (int n = 0; n < 4; ++n) {
      int col = blockIdx.y * 128 + wc * 64 + n * 16 + l15;
      if constexpr (EPI == EP_VT) {
        // write V transposed: Vt[b][h][d][s], pack 4 consecutive s
        int bidx = row0 >> 11, s0 = row0 & 2047;
        int hh = col >> 6, dd = col & 63;
        u16x4 pk;
#pragma unroll
        for (int r = 0; r < 4; ++r) pk[r] = bfbits(acc[m][n][r] + bia[n]);
        *(u16x4*)((bf16*)Cout + (((size_t)bidx * HEADS + hh) * D_KH + dd) * SEQ + s0) = pk;
      } else {
#pragma unroll
        for (int r = 0; r < 4; ++r) {
          float v = acc[m][n][r] + bia[n];
          if constexpr (EPI == EP_RELU) v = fmaxf(v, 0.f);
          if constexpr (EPI == EP_F32)
            ((float*)Cout)[(size_t)(row0 + r) * N + col] = v;
          else
            ((bf16*)Cout)[(size_t)(row0 + r) * N + col] = (bf16)v;
        }
      }
    }
  }
}

// ---------------- flash attention v2 -----------------
// grid (SEQ/128, BATCH*HEADS); 4 waves x 32 q-rows; KVBLK=64.
// Swapped QK^T (S^T = K @ Q^T) so softmax is mostly in-lane (2 shfls/row-set);
// K/V cooperatively staged to LDS (global_load_lds, XOR-swizzled via
// pre-swizzled global source), double-buffered, 1 barrier/tile.
__global__ __launch_bounds__(256, 3) void k_attn(
    const bf16* __restrict__ Q, const bf16* __restrict__ Kb,
    const bf16* __restrict__ Vt, const int* __restrict__ mask,
    bf16* __restrict__ O) {
  __shared__ bf16 Ks[2][64 * 64];
  __shared__ bf16 Vs[2][64 * 64];
  __shared__ bf16 Pt[4][32][72];  // per-wave P[q][kv], +8 pad
  const int tid = threadIdx.x;
  const int lane = tid & 63, w = tid >> 6;
  const int l15 = lane & 15, l4 = lane >> 4;
  const int bh = blockIdx.y, b = bh >> 4, h = bh & 15;
  const size_t qrow0 = (size_t)b * SEQ + blockIdx.x * 128 + w * 32;
  const bf16* Kbase = Kb + (size_t)b * SEQ * D_MODEL + h * 64;
  const bf16* Vbase = Vt + (size_t)bh * D_KH * SEQ;
  const int* mbase = mask + b * SEQ;
  constexpr float C = 0.18033688011f;  // (1/sqrt(64)) * log2(e)
  constexpr float THR = 64.0f;         // defer-max: 8.0 / 0.125 in raw units

  bf16x8 qf[2][2];
#pragma unroll
  for (int m = 0; m < 2; ++m)
#pragma unroll
    for (int ks = 0; ks < 2; ++ks)
      qf[m][ks] = *(const bf16x8*)&Q[(qrow0 + m * 16 + l15) * D_MODEL + h * 64 + ks * 32 + l4 * 8];

  f32x4 o[2][4] = {};
  float mrun[2] = {-1e30f, -1e30f};
  float lrun[2] = {0.f, 0.f};

  auto stage = [&](int buf, int kv0) {
#pragma unroll
    for (int i = 0; i < 2; ++i) {
      int o_ = tid + i * 256;               // 16B-chunk index 0..511
      int row = o_ >> 3;                    // 0..63
      int ch = (o_ & 7) ^ (row & 7);        // inverse-swizzled source chunk
      gload_lds16(Kbase + (size_t)(kv0 + row) * D_MODEL + ch * 8,
                  (char*)&Ks[buf][0] + o_ * 16);
      gload_lds16(Vbase + (size_t)row * SEQ + kv0 + ch * 8,
                  (char*)&Vs[buf][0] + o_ * 16);
    }
  };

  stage(0, 0);
  __syncthreads();

  for (int kv0 = 0; kv0 < SEQ; kv0 += 64) {
    const int cur = (kv0 >> 6) & 1;
    if (kv0 + 64 < SEQ) stage(cur ^ 1, kv0 + 64);
    const bf16* Kc = &Ks[cur][0];
    const bf16* Vc = &Vs[cur][0];

    // S^T = K @ Q^T : sf[m][n] rows kv = n*16+l4*4+r, col q = m*16+l15
    f32x4 sf[2][4] = {};
#pragma unroll
    for (int ks = 0; ks < 2; ++ks)
#pragma unroll
      for (int n = 0; n < 4; ++n) {
        int r = n * 16 + l15;
        bf16x8 kf = *(const bf16x8*)&Kc[r * 64 + ((ks * 32 + l4 * 8) ^ ((r & 7) << 3))];
#pragma unroll
        for (int m = 0; m < 2; ++m)
          sf[m][n] = __builtin_amdgcn_mfma_f32_16x16x32_bf16(kf, qf[m][ks], sf[m][n], 0, 0, 0);
      }

    // mask (kv = kv0 + n*16 + l4*4 + r)
    int4 mk[4];
#pragma unroll
    for (int n = 0; n < 4; ++n)
      mk[n] = *(const int4*)&mbase[kv0 + n * 16 + l4 * 4];
#pragma unroll
    for (int n = 0; n < 4; ++n)
#pragma unroll
      for (int r = 0; r < 4; ++r)
        if (((const int*)&mk[n])[r] == 0) {
          sf[0][n][r] = -1e30f;
          sf[1][n][r] = -1e30f;
        }

    // online softmax, per m (each lane owns q = m*16+l15; kv spread in-lane + l4)
#pragma unroll
    for (int m = 0; m < 2; ++m) {
      float pm = -1e30f;
#pragma unroll
      for (int n = 0; n < 4; ++n)
#pragma unroll
        for (int r = 0; r < 4; ++r) pm = fmaxf(pm, sf[m][n][r]);
      pm = fmaxf(pm, __shfl_xor(pm, 16));
      pm = fmaxf(pm, __shfl_xor(pm, 32));
      if (__any(pm > mrun[m] + THR)) {
        float mnew = fmaxf(mrun[m], pm);
        float alpha = exp2f((mrun[m] - mnew) * C);
        lrun[m] *= alpha;
        mrun[m] = mnew;
#pragma unroll
        for (int r = 0; r < 4; ++r) {
          float arow = __shfl(alpha, l4 * 4 + r);  // alpha for o-row q=m*16+l4*4+r
#pragma unroll
          for (int n = 0; n < 4; ++n) o[m][n][r] *= arow;
        }
      }
      float mC = -mrun[m] * C;
      float ps = 0.f;
#pragma unroll
      for (int n = 0; n < 4; ++n)
#pragma unroll
        for (int r = 0; r < 4; ++r) {
          float p = exp2f(fmaf(sf[m][n][r], C, mC));
          sf[m][n][r] = p;
          ps += p;
        }
      ps += __shfl_xor(ps, 16);
      ps += __shfl_xor(ps, 32);
      lrun[m] += ps;
      // P -> LDS: 4 consecutive kv per lane = one 8B write per (m,n)
#pragma unroll
      for (int n = 0; n < 4; ++n) {
        u16x4 pk = {bfbits(sf[m][n][0]), bfbits(sf[m][n][1]),
                    bfbits(sf[m][n][2]), bfbits(sf[m][n][3])};
        *(u16x4*)&Pt[w][m * 16 + l15][n * 16 + l4 * 4] = pk;
      }
    }

    // PV: o[m][n] += P[q][kv] @ V[kv][d]
#pragma unroll
    for (int ks = 0; ks < 2; ++ks) {
      bf16x8 pa[2];
#pragma unroll
      for (int m = 0; m < 2; ++m)
        pa[m] = *(const bf16x8*)&Pt[w][m * 16 + l15][ks * 32 + l4 * 8];
#pragma unroll
      for (int n = 0; n < 4; ++n) {
        int d = n * 16 + l15;
        bf16x8 vf = *(const bf16x8*)&Vc[d * 64 + ((ks * 32 + l4 * 8) ^ ((d & 7) << 3))];
#pragma unroll
        for (int m = 0; m < 2; ++m)
          o[m][n] = __builtin_amdgcn_mfma_f32_16x16x32_bf16(pa[m], vf, o[m][n], 0, 0, 0);
      }
    }
    __syncthreads();
  }

  // epilogue: normalize rows (lrun lives at lane l15 = row; fetch via shfl)
#pragma unroll
  for (int m = 0; m < 2; ++m) {
    float inv[4];
#pragma unroll
    for (int r = 0; r < 4; ++r)
      inv[r] = 1.0f / __shfl(lrun[m], l4 * 4 + r);
#pragma unroll
    for (int n = 0; n < 4; ++n)
#pragma unroll
      for (int r = 0; r < 4; ++r)
        O[(qrow0 + m * 16 + l4 * 4 + r) * D_MODEL + h * 64 + n * 16 + l15] =
            (bf16)(o[m][n][r] * inv[r]);
  }
}

// ---------------- fused residual add + LayerNorm (1 block / row) ---------
__global__ __launch_bounds__(256) void k_add_ln(
    const float* __restrict__ a, const float* __restrict__ b,
    const float* __restrict__ g, const float* __restrict__ be,
    float* __restrict__ yf, bf16* __restrict__ yb) {
  const int t = threadIdx.x;
  const size_t base = (size_t)blockIdx.x * D_MODEL + t * 4;
  float4 va = *(const float4*)(a + base);
  float4 vb = *(const float4*)(b + base);
  float v0 = va.x + vb.x, v1 = va.y + vb.y, v2 = va.z + vb.z, v3 = va.w + vb.w;
  float s  = v0 + v1 + v2 + v3;
  float s2 = v0 * v0 + v1 * v1 + v2 * v2 + v3 * v3;
#pragma unroll
  for (int off = 1; off < 64; off <<= 1) {
    s  += __shfl_xor(s, off);
    s2 += __shfl_xor(s2, off);
  }
  __shared__ float red1[4], red2[4];
  int w = t >> 6;
  if ((t & 63) == 0) { red1[w] = s; red2[w] = s2; }
  __syncthreads();
  s  = red1[0] + red1[1] + red1[2] + red1[3];
  s2 = red2[0] + red2[1] + red2[2] + red2[3];
  float mu  = s * (1.f / D_MODEL);
  float var = s2 * (1.f / D_MODEL) - mu * mu;
  float rstd = rsqrtf(var + 1e-5f);
  float4 vg  = *(const float4*)(g + t * 4);
  float4 vbe = *(const float4*)(be + t * 4);
  float y0 = (v0 - mu) * rstd * vg.x + vbe.x;
  float y1 = (v1 - mu) * rstd * vg.y + vbe.y;
  float y2 = (v2 - mu) * rstd * vg.z + vbe.z;
  float y3 = (v3 - mu) * rstd * vg.w + vbe.w;
  *(float4*)(yf + base) = make_float4(y0, y1, y2, y3);
  if (yb) {
    u16x4 pk = {bfbits(y0), bfbits(y1), bfbits(y2), bfbits(y3)};
    *(u16x4*)(yb + base) = pk;
  }
}

// ---------------- orchestration ----------------
extern "C" void kernel_launch(void* const* d_in, const int* in_sizes, int n_in,
                              void* d_out, int out_size, void* d_ws, size_t ws_size,
                              hipStream_t stream) {
  const float* x   = (const float*)d_in[0];
  const int*  mask = (const int*)d_in[1];
  const float* Wq  = (const float*)d_in[2];
  const float* bq  = (const float*)d_in[3];
  const float* Wk  = (const float*)d_in[4];
  const float* bk_ = (const float*)d_in[5];
  const float* Wv  = (const float*)d_in[6];
  const float* bv  = (const float*)d_in[7];
  const float* Wo  = (const float*)d_in[8];
  const float* bo  = (const float*)d_in[9];
  const float* W1  = (const float*)d_in[10];
  const float* b1  = (const float*)d_in[11];
  const float* W2  = (const float*)d_in[12];
  const float* b2  = (const float*)d_in[13];
  const float* g1  = (const float*)d_in[14];
  const float* be1 = (const float*)d_in[15];
  const float* g2  = (const float*)d_in[16];
  const float* be2 = (const float*)d_in[17];

  char* ws = (char*)d_ws;
  const size_t MB = 1ull << 20;
  bf16*  xb   = (bf16*)(ws + 0);         // 16MB, later attention output O
  bf16*  Qb   = (bf16*)(ws + 16 * MB);   // 16MB
  bf16*  Kbuf = (bf16*)(ws + 32 * MB);   // 16MB
  bf16*  Vt   = (bf16*)(ws + 48 * MB);   // 16MB [B,H,64,S]
  bf16*  Hb   = (bf16*)(ws + 0);         // 64MB FFN hidden (reuse)
  float* f32a = (float*)(ws + 64 * MB);  // 32MB attn-proj f32 / ffn f32
  float* x1f  = (float*)(ws + 96 * MB);  // 32MB
  bf16*  x1b  = (bf16*)(ws + 128 * MB);  // 16MB
  bf16*  Wqt  = (bf16*)(ws + 144 * MB);
  bf16*  Wkt  = (bf16*)(ws + 146 * MB);
  bf16*  Wvt  = (bf16*)(ws + 148 * MB);
  bf16*  Wot  = (bf16*)(ws + 150 * MB);
  bf16*  W1t  = (bf16*)(ws + 152 * MB);  // 8MB [4096,1024]
  bf16*  W2t  = (bf16*)(ws + 160 * MB);  // 8MB [1024,4096]
  bf16*  Ob   = xb;

  k_cast_bf16<<<MROWS * D_MODEL / (256 * 8), 256, 0, stream>>>(x, xb);
  k_transpose_cast<<<dim3(16, 16), 256, 0, stream>>>(Wq, Wqt, 1024, 1024);
  k_transpose_cast<<<dim3(16, 16), 256, 0, stream>>>(Wk, Wkt, 1024, 1024);
  k_transpose_cast<<<dim3(16, 16), 256, 0, stream>>>(Wv, Wvt, 1024, 1024);
  k_transpose_cast<<<dim3(16, 16), 256, 0, stream>>>(Wo, Wot, 1024, 1024);
  k_transpose_cast<<<dim3(16, 64), 256, 0, stream>>>(W1, W1t, 1024, 4096);
  k_transpose_cast<<<dim3(64, 16), 256, 0, stream>>>(W2, W2t, 4096, 1024);

  k_gemm_bt<EP_BF16><<<dim3(64, 8), 256, 0, stream>>>(xb, Wqt, bq, Qb, 1024, 1024);
  k_gemm_bt<EP_BF16><<<dim3(64, 8), 256, 0, stream>>>(xb, Wkt, bk_, Kbuf, 1024, 1024);
  k_gemm_bt<EP_VT  ><<<dim3(64, 8), 256, 0, stream>>>(xb, Wvt, bv, Vt, 1024, 1024);

  k_attn<<<dim3(16, 64), 256, 0, stream>>>(Qb, Kbuf, Vt, mask, Ob);

  k_gemm_bt<EP_F32><<<dim3(64, 8), 256, 0, stream>>>(Ob, Wot, bo, f32a, 1024, 1024);
  k_add_ln<<<MROWS, 256, 0, stream>>>(x, f32a, g1, be1, x1f, x1b);

  k_gemm_bt<EP_RELU><<<dim3(64, 32), 256, 0, stream>>>(x1b, W1t, b1, Hb, 4096, 1024);
  k_gemm_bt<EP_F32><<<dim3(64, 8), 256, 0, stream>>>(Hb, W2t, b2, f32a, 1024, 4096);
  k_add_ln<<<MROWS, 256, 0, stream>>>(x1f, f32a, g2, be2, (float*)d_out, nullptr);
}

// Round 3
// 433.697 us; speedup vs baseline: 1.4586x; 1.1185x over previous
//
#include <hip/hip_runtime.h>
#include <hip/hip_bf16.h>
#include <cstdint>
#include <cstddef>

typedef __bf16 bf16;
typedef __bf16 bf16x8 __attribute__((ext_vector_type(8)));
typedef float  f32x4  __attribute__((ext_vector_type(4)));
typedef unsigned short u16x4 __attribute__((ext_vector_type(4)));

static constexpr int D_MODEL = 1024;
static constexpr int HEADS   = 16;
static constexpr int D_KH    = 64;     // per-head dim
static constexpr int D_FF    = 4096;
static constexpr int BATCH   = 4;
static constexpr int SEQ     = 2048;
static constexpr int MROWS   = BATCH * SEQ;  // 8192

__device__ __forceinline__ unsigned short bfbits(float f) {
  return __builtin_bit_cast(unsigned short, (bf16)f);
}

// global -> LDS direct copy, 16B per lane. LDS dest must be linear
// (wave-uniform base + lane*16).
__device__ __forceinline__ void gload_lds16(const void* g, void* l) {
  __builtin_amdgcn_global_load_lds(
      (__attribute__((address_space(1))) uint32_t*)(uintptr_t)g,
      (__attribute__((address_space(3))) uint32_t*)(uintptr_t)l, 16, 0, 0);
}

// ---------------- elementwise f32 -> bf16 cast (8/thread) ----------------
__global__ void k_cast_bf16(const float* __restrict__ in, bf16* __restrict__ out) {
  int i = (blockIdx.x * 256 + threadIdx.x) * 8;
  const float4* p = (const float4*)(in + i);
  float4 a = p[0], b = p[1];
  bf16x8 v;
  v[0] = (bf16)a.x; v[1] = (bf16)a.y; v[2] = (bf16)a.z; v[3] = (bf16)a.w;
  v[4] = (bf16)b.x; v[5] = (bf16)b.y; v[6] = (bf16)b.z; v[7] = (bf16)b.w;
  *(bf16x8*)(out + i) = v;
}

// ---------------- W [K,N] f32  ->  Wt [N,K] bf16 (64x64 LDS tiles) -------
__global__ void k_transpose_cast(const float* __restrict__ W, bf16* __restrict__ Wt,
                                 int K, int N) {
  __shared__ float tile[64][65];
  int k0 = blockIdx.x * 64, n0 = blockIdx.y * 64;
  int c = threadIdx.x & 63, r0 = threadIdx.x >> 6;
#pragma unroll
  for (int i = 0; i < 16; ++i) {
    int r = r0 + i * 4;
    tile[r][c] = W[(size_t)(k0 + r) * N + n0 + c];
  }
  __syncthreads();
#pragma unroll
  for (int i = 0; i < 16; ++i) {
    int r = r0 + i * 4;
    Wt[(size_t)(n0 + r) * K + k0 + c] = (bf16)tile[c][r];
  }
}

// ---------------- GEMM v2: C[M,N] = A[M,K] @ Bt[N,K]^T + bias ------------
// BM=256, BN=128, BK=64; 8 waves (4M x 2N), per-wave 64x64 (4x4 frags).
// Dynamic LDS 96KB: A dbuf 2x[256][64], B dbuf 2x[128][64], bf16,
// (row&7)-XOR swizzled (pre-swizzled global source, swizzled ds_read).
// Per K-step: 2 phases (ks=0/1), each {8 ds_read_b128 -> lgkmcnt(0) ->
// setprio(1) 16 MFMA setprio(0) -> raw s_barrier}; next step's 6 staging
// loads issued at phase-0 start, drained by one vmcnt(0) at step end.
enum { EP_BF16 = 0, EP_RELU = 1, EP_F32 = 2, EP_VT = 3 };

template <int EPI>
__global__ __launch_bounds__(512, 2) void k_gemm2(
    const bf16* __restrict__ A, const bf16* __restrict__ Bt,
    const float* __restrict__ bias, void* __restrict__ Cout,
    int N, int K) {
  extern __shared__ char smem[];
  char* Asm = smem;          // 2 * 256*64*2 = 65536 B
  char* Bsm = smem + 65536;  // 2 * 128*64*2 = 32768 B
  const int tid = threadIdx.x;
  const int lane = tid & 63;
  const int wid = tid >> 6;
  const int wr = wid & 3, wc = wid >> 2;
  const int l15 = lane & 15, l4 = lane >> 4;
  const int bx = blockIdx.x, by = blockIdx.y;
  const int NS = K >> 6;

  // per-thread staging slices (pre-swizzled global source, linear LDS dest)
  const bf16* gA[4];
  const bf16* gB[2];
  int ldsA[4], ldsB[2];
#pragma unroll
  for (int i = 0; i < 4; ++i) {
    int c = tid + i * 512;
    int row = c >> 3, k16 = c & 7;
    gA[i] = A + (size_t)(bx * 256 + row) * K + (k16 ^ (row & 7)) * 8;
    ldsA[i] = c * 16;
  }
#pragma unroll
  for (int i = 0; i < 2; ++i) {
    int c = tid + i * 512;
    int row = c >> 3, k16 = c & 7;
    gB[i] = Bt + (size_t)(by * 128 + row) * K + (k16 ^ (row & 7)) * 8;
    ldsB[i] = c * 16;
  }

  f32x4 acc[4][4] = {};

  auto stage = [&](int d) {
#pragma unroll
    for (int i = 0; i < 4; ++i)
      gload_lds16(gA[i], Asm + d * 32768 + ldsA[i]);
#pragma unroll
    for (int i = 0; i < 2; ++i)
      gload_lds16(gB[i], Bsm + d * 16384 + ldsB[i]);
#pragma unroll
    for (int i = 0; i < 4; ++i) gA[i] += 64;
#pragma unroll
    for (int i = 0; i < 2; ++i) gB[i] += 64;
  };

  stage(0);
  asm volatile("s_waitcnt vmcnt(0)" ::: "memory");
  __builtin_amdgcn_s_barrier();

  const int swzA = (l4 ^ (l15 & 7)) * 16;
  const int swzB = ((4 + l4) ^ (l15 & 7)) * 16;

  for (int s = 0; s < NS; ++s) {
    const int d = s & 1;
    const char* Ad = Asm + d * 32768;
    const char* Bd = Bsm + d * 16384;
    if (s + 1 < NS) stage(d ^ 1);
    bf16x8 a[4], b[4];
    // ---- phase 0 (ks=0) ----
#pragma unroll
    for (int m = 0; m < 4; ++m)
      a[m] = *(const bf16x8*)(Ad + (wr * 64 + m * 16 + l15) * 128 + swzA);
#pragma unroll
    for (int n = 0; n < 4; ++n)
      b[n] = *(const bf16x8*)(Bd + (wc * 64 + n * 16 + l15) * 128 + swzA);
    asm volatile("s_waitcnt lgkmcnt(0)" ::: "memory");
    __builtin_amdgcn_sched_barrier(0);
    __builtin_amdgcn_s_setprio(1);
#pragma unroll
    for (int m = 0; m < 4; ++m)
#pragma unroll
      for (int n = 0; n < 4; ++n)
        acc[m][n] = __builtin_amdgcn_mfma_f32_16x16x32_bf16(a[m], b[n], acc[m][n], 0, 0, 0);
    __builtin_amdgcn_s_setprio(0);
    __builtin_amdgcn_s_barrier();
    // ---- phase 1 (ks=1) ----
#pragma unroll
    for (int m = 0; m < 4; ++m)
      a[m] = *(const bf16x8*)(Ad + (wr * 64 + m * 16 + l15) * 128 + swzB);
#pragma unroll
    for (int n = 0; n < 4; ++n)
      b[n] = *(const bf16x8*)(Bd + (wc * 64 + n * 16 + l15) * 128 + swzB);
    asm volatile("s_waitcnt lgkmcnt(0)" ::: "memory");
    __builtin_amdgcn_sched_barrier(0);
    __builtin_amdgcn_s_setprio(1);
#pragma unroll
    for (int m = 0; m < 4; ++m)
#pragma unroll
      for (int n = 0; n < 4; ++n)
        acc[m][n] = __builtin_amdgcn_mfma_f32_16x16x32_bf16(a[m], b[n], acc[m][n], 0, 0, 0);
    __builtin_amdgcn_s_setprio(0);
    asm volatile("s_waitcnt vmcnt(0)" ::: "memory");
    __builtin_amdgcn_s_barrier();
  }

  float bia[4];
#pragma unroll
  for (int n = 0; n < 4; ++n)
    bia[n] = bias[by * 128 + wc * 64 + n * 16 + l15];
#pragma unroll
  for (int m = 0; m < 4; ++m) {
    int row0 = bx * 256 + wr * 64 + m * 16 + l4 * 4;
#pragma unroll
    for (int n = 0; n < 4; ++n) {
      int col = by * 128 + wc * 64 + n * 16 + l15;
      if constexpr (EPI == EP_VT) {
        int bidx = row0 >> 11, s0 = row0 & 2047;
        int hh = col >> 6, dd = col & 63;
        u16x4 pk;
#pragma unroll
        for (int r = 0; r < 4; ++r) pk[r] = bfbits(acc[m][n][r] + bia[n]);
        *(u16x4*)((bf16*)Cout + (((size_t)bidx * HEADS + hh) * D_KH + dd) * SEQ + s0) = pk;
      } else {
#pragma unroll
        for (int r = 0; r < 4; ++r) {
          float v = acc[m][n][r] + bia[n];
          if constexpr (EPI == EP_RELU) v = fmaxf(v, 0.f);
          if constexpr (EPI == EP_F32)
            ((float*)Cout)[(size_t)(row0 + r) * N + col] = v;
          else
            ((bf16*)Cout)[(size_t)(row0 + r) * N + col] = (bf16)v;
        }
      }
    }
  }
}

// ---------------- flash attention -----------------
// grid (SEQ/128, BATCH*HEADS); 4 waves x 32 q-rows; KVBLK=64.
__global__ __launch_bounds__(256, 3) void k_attn(
    const bf16* __restrict__ Q, const bf16* __restrict__ Kb,
    const bf16* __restrict__ Vt, const int* __restrict__ mask,
    bf16* __restrict__ O) {
  __shared__ bf16 Ks[2][64 * 64];
  __shared__ bf16 Vs[2][64 * 64];
  __shared__ bf16 Pt[4][32][72];
  const int tid = threadIdx.x;
  const int lane = tid & 63, w = tid >> 6;
  const int l15 = lane & 15, l4 = lane >> 4;
  const int bh = blockIdx.y, b = bh >> 4, h = bh & 15;
  const size_t qrow0 = (size_t)b * SEQ + blockIdx.x * 128 + w * 32;
  const bf16* Kbase = Kb + (size_t)b * SEQ * D_MODEL + h * 64;
  const bf16* Vbase = Vt + (size_t)bh * D_KH * SEQ;
  const int* mbase = mask + b * SEQ;
  constexpr float C = 0.18033688011f;  // (1/sqrt(64)) * log2(e)
  constexpr float THR = 64.0f;         // defer-max threshold (raw units)

  bf16x8 qf[2][2];
#pragma unroll
  for (int m = 0; m < 2; ++m)
#pragma unroll
    for (int ks = 0; ks < 2; ++ks)
      qf[m][ks] = *(const bf16x8*)&Q[(qrow0 + m * 16 + l15) * D_MODEL + h * 64 + ks * 32 + l4 * 8];

  f32x4 o[2][4] = {};
  float mrun[2] = {-1e30f, -1e30f};
  float lrun[2] = {0.f, 0.f};

  auto stage = [&](int buf, int kv0) {
#pragma unroll
    for (int i = 0; i < 2; ++i) {
      int o_ = tid + i * 256;
      int row = o_ >> 3;
      int ch = (o_ & 7) ^ (row & 7);
      gload_lds16(Kbase + (size_t)(kv0 + row) * D_MODEL + ch * 8,
                  (char*)&Ks[buf][0] + o_ * 16);
      gload_lds16(Vbase + (size_t)row * SEQ + kv0 + ch * 8,
                  (char*)&Vs[buf][0] + o_ * 16);
    }
  };

  stage(0, 0);
  __syncthreads();

  for (int kv0 = 0; kv0 < SEQ; kv0 += 64) {
    const int cur = (kv0 >> 6) & 1;
    if (kv0 + 64 < SEQ) stage(cur ^ 1, kv0 + 64);
    const bf16* Kc = &Ks[cur][0];
    const bf16* Vc = &Vs[cur][0];

    // S^T = K @ Q^T
    f32x4 sf[2][4] = {};
    __builtin_amdgcn_s_setprio(1);
#pragma unroll
    for (int ks = 0; ks < 2; ++ks)
#pragma unroll
      for (int n = 0; n < 4; ++n) {
        int r = n * 16 + l15;
        bf16x8 kf = *(const bf16x8*)&Kc[r * 64 + ((ks * 32 + l4 * 8) ^ ((r & 7) << 3))];
#pragma unroll
        for (int m = 0; m < 2; ++m)
          sf[m][n] = __builtin_amdgcn_mfma_f32_16x16x32_bf16(kf, qf[m][ks], sf[m][n], 0, 0, 0);
      }
    __builtin_amdgcn_s_setprio(0);

    // mask (wave-uniform fast path: skip when all-ones)
    int4 mk[4];
#pragma unroll
    for (int n = 0; n < 4; ++n)
      mk[n] = *(const int4*)&mbase[kv0 + n * 16 + l4 * 4];
    int allm = 1;
#pragma unroll
    for (int n = 0; n < 4; ++n)
      allm &= (mk[n].x & mk[n].y & mk[n].z & mk[n].w);
    if (__builtin_expect(!__all(allm != 0), 0)) {
#pragma unroll
      for (int n = 0; n < 4; ++n)
#pragma unroll
        for (int r = 0; r < 4; ++r)
          if (((const int*)&mk[n])[r] == 0) {
            sf[0][n][r] = -1e30f;
            sf[1][n][r] = -1e30f;
          }
    }

    // online softmax (per m; kv in-lane + split over l4 halves)
#pragma unroll
    for (int m = 0; m < 2; ++m) {
      float pm = -1e30f;
#pragma unroll
      for (int n = 0; n < 4; ++n)
#pragma unroll
        for (int r = 0; r < 4; ++r) pm = fmaxf(pm, sf[m][n][r]);
      pm = fmaxf(pm, __shfl_xor(pm, 16));
      pm = fmaxf(pm, __shfl_xor(pm, 32));
      if (__any(pm > mrun[m] + THR)) {
        float mnew = fmaxf(mrun[m], pm);
        float alpha = exp2f((mrun[m] - mnew) * C);
        lrun[m] *= alpha;
        mrun[m] = mnew;
#pragma unroll
        for (int r = 0; r < 4; ++r) {
          float arow = __shfl(alpha, l4 * 4 + r);
#pragma unroll
          for (int n = 0; n < 4; ++n) o[m][n][r] *= arow;
        }
      }
      float mC = -mrun[m] * C;
      float ps = 0.f;
#pragma unroll
      for (int n = 0; n < 4; ++n)
#pragma unroll
        for (int r = 0; r < 4; ++r) {
          float p = exp2f(fmaf(sf[m][n][r], C, mC));
          sf[m][n][r] = p;
          ps += p;
        }
      ps += __shfl_xor(ps, 16);
      ps += __shfl_xor(ps, 32);
      lrun[m] += ps;
#pragma unroll
      for (int n = 0; n < 4; ++n) {
        u16x4 pk = {bfbits(sf[m][n][0]), bfbits(sf[m][n][1]),
                    bfbits(sf[m][n][2]), bfbits(sf[m][n][3])};
        *(u16x4*)&Pt[w][m * 16 + l15][n * 16 + l4 * 4] = pk;
      }
    }

    // PV
#pragma unroll
    for (int ks = 0; ks < 2; ++ks) {
      bf16x8 pa[2];
#pragma unroll
      for (int m = 0; m < 2; ++m)
        pa[m] = *(const bf16x8*)&Pt[w][m * 16 + l15][ks * 32 + l4 * 8];
      __builtin_amdgcn_s_setprio(1);
#pragma unroll
      for (int n = 0; n < 4; ++n) {
        int d = n * 16 + l15;
        bf16x8 vf = *(const bf16x8*)&Vc[d * 64 + ((ks * 32 + l4 * 8) ^ ((d & 7) << 3))];
#pragma unroll
        for (int m = 0; m < 2; ++m)
          o[m][n] = __builtin_amdgcn_mfma_f32_16x16x32_bf16(pa[m], vf, o[m][n], 0, 0, 0);
      }
      __builtin_amdgcn_s_setprio(0);
    }
    __syncthreads();
  }

#pragma unroll
  for (int m = 0; m < 2; ++m) {
    float inv[4];
#pragma unroll
    for (int r = 0; r < 4; ++r)
      inv[r] = 1.0f / __shfl(lrun[m], l4 * 4 + r);
#pragma unroll
    for (int n = 0; n < 4; ++n)
#pragma unroll
      for (int r = 0; r < 4; ++r)
        O[(qrow0 + m * 16 + l4 * 4 + r) * D_MODEL + h * 64 + n * 16 + l15] =
            (bf16)(o[m][n][r] * inv[r]);
  }
}

// ---------------- fused residual add + LayerNorm (1 block / row) ---------
__global__ __launch_bounds__(256) void k_add_ln(
    const float* __restrict__ a, const float* __restrict__ b,
    const float* __restrict__ g, const float* __restrict__ be,
    float* __restrict__ yf, bf16* __restrict__ yb) {
  const int t = threadIdx.x;
  const size_t base = (size_t)blockIdx.x * D_MODEL + t * 4;
  float4 va = *(const float4*)(a + base);
  float4 vb = *(const float4*)(b + base);
  float v0 = va.x + vb.x, v1 = va.y + vb.y, v2 = va.z + vb.z, v3 = va.w + vb.w;
  float s  = v0 + v1 + v2 + v3;
  float s2 = v0 * v0 + v1 * v1 + v2 * v2 + v3 * v3;
#pragma unroll
  for (int off = 1; off < 64; off <<= 1) {
    s  += __shfl_xor(s, off);
    s2 += __shfl_xor(s2, off);
  }
  __shared__ float red1[4], red2[4];
  int w = t >> 6;
  if ((t & 63) == 0) { red1[w] = s; red2[w] = s2; }
  __syncthreads();
  s  = red1[0] + red1[1] + red1[2] + red1[3];
  s2 = red2[0] + red2[1] + red2[2] + red2[3];
  float mu  = s * (1.f / D_MODEL);
  float var = s2 * (1.f / D_MODEL) - mu * mu;
  float rstd = rsqrtf(var + 1e-5f);
  float4 vg  = *(const float4*)(g + t * 4);
  float4 vbe = *(const float4*)(be + t * 4);
  float y0 = (v0 - mu) * rstd * vg.x + vbe.x;
  float y1 = (v1 - mu) * rstd * vg.y + vbe.y;
  float y2 = (v2 - mu) * rstd * vg.z + vbe.z;
  float y3 = (v3 - mu) * rstd * vg.w + vbe.w;
  *(float4*)(yf + base) = make_float4(y0, y1, y2, y3);
  if (yb) {
    u16x4 pk = {bfbits(y0), bfbits(y1), bfbits(y2), bfbits(y3)};
    *(u16x4*)(yb + base) = pk;
  }
}

// ---------------- orchestration ----------------
extern "C" void kernel_launch(void* const* d_in, const int* in_sizes, int n_in,
                              void* d_out, int out_size, void* d_ws, size_t ws_size,
                              hipStream_t stream) {
  const float* x   = (const float*)d_in[0];
  const int*  mask = (const int*)d_in[1];
  const float* Wq  = (const float*)d_in[2];
  const float* bq  = (const float*)d_in[3];
  const float* Wk  = (const float*)d_in[4];
  const float* bk_ = (const float*)d_in[5];
  const float* Wv  = (const float*)d_in[6];
  const float* bv  = (const float*)d_in[7];
  const float* Wo  = (const float*)d_in[8];
  const float* bo  = (const float*)d_in[9];
  const float* W1  = (const float*)d_in[10];
  const float* b1  = (const float*)d_in[11];
  const float* W2  = (const float*)d_in[12];
  const float* b2  = (const float*)d_in[13];
  const float* g1  = (const float*)d_in[14];
  const float* be1 = (const float*)d_in[15];
  const float* g2  = (const float*)d_in[16];
  const float* be2 = (const float*)d_in[17];

  char* ws = (char*)d_ws;
  const size_t MB = 1ull << 20;
  bf16*  xb   = (bf16*)(ws + 0);         // 16MB, later attention output O
  bf16*  Qb   = (bf16*)(ws + 16 * MB);   // 16MB
  bf16*  Kbuf = (bf16*)(ws + 32 * MB);   // 16MB
  bf16*  Vt   = (bf16*)(ws + 48 * MB);   // 16MB [B,H,64,S]
  bf16*  Hb   = (bf16*)(ws + 0);         // 64MB FFN hidden (reuse)
  float* f32a = (float*)(ws + 64 * MB);  // 32MB attn-proj f32 / ffn f32
  float* x1f  = (float*)(ws + 96 * MB);  // 32MB
  bf16*  x1b  = (bf16*)(ws + 128 * MB);  // 16MB
  bf16*  Wqt  = (bf16*)(ws + 144 * MB);
  bf16*  Wkt  = (bf16*)(ws + 146 * MB);
  bf16*  Wvt  = (bf16*)(ws + 148 * MB);
  bf16*  Wot  = (bf16*)(ws + 150 * MB);
  bf16*  W1t  = (bf16*)(ws + 152 * MB);  // 8MB [4096,1024]
  bf16*  W2t  = (bf16*)(ws + 160 * MB);  // 8MB [1024,4096]
  bf16*  Ob   = xb;

  const int SMEM = 98304;
  hipFuncSetAttribute(reinterpret_cast<const void*>(&k_gemm2<EP_BF16>),
                      hipFuncAttributeMaxDynamicSharedMemorySize, SMEM);
  hipFuncSetAttribute(reinterpret_cast<const void*>(&k_gemm2<EP_VT>),
                      hipFuncAttributeMaxDynamicSharedMemorySize, SMEM);
  hipFuncSetAttribute(reinterpret_cast<const void*>(&k_gemm2<EP_F32>),
                      hipFuncAttributeMaxDynamicSharedMemorySize, SMEM);
  hipFuncSetAttribute(reinterpret_cast<const void*>(&k_gemm2<EP_RELU>),
                      hipFuncAttributeMaxDynamicSharedMemorySize, SMEM);

  k_cast_bf16<<<MROWS * D_MODEL / (256 * 8), 256, 0, stream>>>(x, xb);
  k_transpose_cast<<<dim3(16, 16), 256, 0, stream>>>(Wq, Wqt, 1024, 1024);
  k_transpose_cast<<<dim3(16, 16), 256, 0, stream>>>(Wk, Wkt, 1024, 1024);
  k_transpose_cast<<<dim3(16, 16), 256, 0, stream>>>(Wv, Wvt, 1024, 1024);
  k_transpose_cast<<<dim3(16, 16), 256, 0, stream>>>(Wo, Wot, 1024, 1024);
  k_transpose_cast<<<dim3(16, 64), 256, 0, stream>>>(W1, W1t, 1024, 4096);
  k_transpose_cast<<<dim3(64, 16), 256, 0, stream>>>(W2, W2t, 4096, 1024);

  k_gemm2<EP_BF16><<<dim3(32, 8), 512, SMEM, stream>>>(xb, Wqt, bq, Qb, 1024, 1024);
  k_gemm2<EP_BF16><<<dim3(32, 8), 512, SMEM, stream>>>(xb, Wkt, bk_, Kbuf, 1024, 1024);
  k_gemm2<EP_VT  ><<<dim3(32, 8), 512, SMEM, stream>>>(xb, Wvt, bv, Vt, 1024, 1024);

  k_attn<<<dim3(16, 64), 256, 0, stream>>>(Qb, Kbuf, Vt, mask, Ob);

  k_gemm2<EP_F32><<<dim3(32, 8), 512, SMEM, stream>>>(Ob, Wot, bo, f32a, 1024, 1024);
  k_add_ln<<<MROWS, 256, 0, stream>>>(x, f32a, g1, be1, x1f, x1b);

  k_gemm2<EP_RELU><<<dim3(32, 32), 512, SMEM, stream>>>(x1b, W1t, b1, Hb, 4096, 1024);
  k_gemm2<EP_F32><<<dim3(32, 8), 512, SMEM, stream>>>(Hb, W2t, b2, f32a, 1024, 4096);
  k_add_ln<<<MROWS, 256, 0, stream>>>(x1f, f32a, g2, be2, (float*)d_out, nullptr);
}